// Round 8
// baseline (47848.016 us; speedup 1.0000x reference)
//
#include <hip/hip_runtime.h>

#define B_ 256
#define S_ 256
#define D_ 64
#define H_ 1024
#define G4 4096
#define TOUT 32

typedef unsigned short u16;
typedef __attribute__((ext_vector_type(8))) short short8;
typedef __attribute__((ext_vector_type(4))) float float4v;

__device__ __forceinline__ float bf2f(u16 b) {
  return __uint_as_float(((unsigned int)b) << 16);
}
__device__ __forceinline__ u16 f2bf(float f) {
  unsigned int u = __float_as_uint(f);
  unsigned int r = (u + 0x7fffu + ((u >> 16) & 1u)) >> 16;
  return (u16)r;
}
__device__ __forceinline__ unsigned pack2(float a, float b) {
  return (unsigned)f2bf(a) | ((unsigned)f2bf(b) << 16);
}
__device__ __forceinline__ float sigm(float x) {
  return 1.f / (1.f + __expf(-x));
}
__device__ __forceinline__ float tanh_(float x) {
  float xc = fminf(fmaxf(x, -15.f), 15.f);
  float e = __expf(2.f * xc);
  return (e - 1.f) / (e + 1.f);
}

// Two-level grid barrier (512 blocks = 8 groups x 64), sense-reversing.
// AGENT-scope atomics + __threadfence() release/acquire give the cross-XCD
// L2 writeback/invalidate that grid-wide data handoff requires (G16).
// bar layout (uints, 128B-padded): gcnt[g]@g*32, ggen[g]@256+g*32, tcnt@512, tgen@544.
__device__ __forceinline__ void gsync(unsigned* bar, int bid) {
  __syncthreads();
  if (threadIdx.x == 0) {
    const int grp = bid & 7;
    unsigned* gcnt = bar + grp * 32;
    unsigned* ggen = bar + 256 + grp * 32;
    unsigned* tcnt = bar + 512;
    unsigned* tgen = bar + 544;
    const unsigned g = __hip_atomic_load(ggen, __ATOMIC_RELAXED, __HIP_MEMORY_SCOPE_AGENT);
    __threadfence();  // release: drain + make this block's writes visible device-wide
    const unsigned prev =
        __hip_atomic_fetch_add(gcnt, 1u, __ATOMIC_ACQ_REL, __HIP_MEMORY_SCOPE_AGENT);
    if (prev == 63) {  // group leader
      const unsigned tg =
          __hip_atomic_load(tgen, __ATOMIC_RELAXED, __HIP_MEMORY_SCOPE_AGENT);
      const unsigned p2 =
          __hip_atomic_fetch_add(tcnt, 1u, __ATOMIC_ACQ_REL, __HIP_MEMORY_SCOPE_AGENT);
      if (p2 == 7) {  // last group: release everyone
        __hip_atomic_store(tcnt, 0u, __ATOMIC_RELAXED, __HIP_MEMORY_SCOPE_AGENT);
        __hip_atomic_fetch_add(tgen, 1u, __ATOMIC_RELEASE, __HIP_MEMORY_SCOPE_AGENT);
      } else {
        while (__hip_atomic_load(tgen, __ATOMIC_ACQUIRE, __HIP_MEMORY_SCOPE_AGENT) == tg)
          __builtin_amdgcn_s_sleep(1);
      }
      __hip_atomic_store(gcnt, 0u, __ATOMIC_RELAXED, __HIP_MEMORY_SCOPE_AGENT);
      __hip_atomic_fetch_add(ggen, 1u, __ATOMIC_RELEASE, __HIP_MEMORY_SCOPE_AGENT);
    } else {
      while (__hip_atomic_load(ggen, __ATOMIC_ACQUIRE, __HIP_MEMORY_SCOPE_AGENT) == g)
        __builtin_amdgcn_s_sleep(1);
    }
    __threadfence();  // acquire: invalidate stale cached lines before reading
  }
  __syncthreads();
}

struct LayerDesc {
  const u16* A0; int lda0;
  const u16* A1; int lda1; int klen0;
  const void* W0; int ldw0;
  const void* W1; int ldw1; int Ktot;
  const float* bias;   // fp32 [4096] original gate-blocked
  const float* wcol;   // fp32 [4096] dec input column, or null
  const float* inp;    // fp32 [B] scalar input, or null
  float* c;
  u16* h;
};

struct Params {
  const float *X, *eWih0, *eWhh0, *eb0, *eWih1, *eWhh1, *eb1;
  const float *dWih0, *dWhh0, *db0, *dWih1, *dWhh1, *db1, *fcW, *fcb;
  float* out;
  unsigned* bar;
  uint4* zbase; int zero16;
  u16 *h0a, *h0b, *h1a, *h1b;
  float *C0, *C1, *INP;
  u16 *XB;
  u16 *Wc0, *Wc1, *Wc2, *Wc3, *Wc4, *Wc5, *Wc6;  // eWih0,eWhh0,eWih1,eWhh1,dWhh0,dWih1,dWhh1
};

// 64x64 tile of one LSTM layer step (round-3 proven body):
// gates = [A0|A1] @ [W0|W1]^T + bias (+inp*wcol), fused cell epilogue.
// tile: x = tile&63 (64 gate-cols, interleaved p=4*J+g via row remap),
//       y = tile>>6 (64 batches). W in ORIGINAL torch layout [4H][K].
template <bool WF32>
__device__ __forceinline__ void layer_tile(const LayerDesc& d, int tile, int tid,
                                           u16 (*As)[72], u16 (*Bs)[72],
                                           float (*Gs)[68])
{
  const int m0 = (tile >> 6) * 64;
  const int n0 = (tile & 63) * 64;
  const int ub = n0 >> 2;        // first hidden unit of this block
  const int r = tid >> 2;        // staging row 0..63
  const int q = tid & 3;         // staging 16-col group
  const int lane = tid & 63;
  const int wv = tid >> 6;
  const int wm = (wv >> 1) * 32;
  const int wn = (wv & 1) * 32;
  const int l16 = lane & 15;
  const int quad = lane >> 4;

  const int klen0 = d.klen0;
  const u16* aw0 = d.A0 + (size_t)(m0 + r) * d.lda0;
  const u16* aw1 = d.A1 + (size_t)(m0 + r) * d.lda1;
  const int orow = (r & 3) * H_ + ub + (r >> 2);  // gate-col n0+r -> original W row
  const u16* bw0_h = (const u16*)d.W0 + (size_t)orow * d.ldw0;
  const u16* bw1_h = (const u16*)d.W1 + (size_t)orow * d.ldw1;
  const float* bw0_f = (const float*)d.W0 + (size_t)orow * d.ldw0;
  const float* bw1_f = (const float*)d.W1 + (size_t)orow * d.ldw1;

  uint4 av0, av1, bv0, bv1;
  float4 xf0, xf1, xf2, xf3;

  auto load_chunk = [&](int kc) {
    const int kg = kc * 64 + q * 16;
    const bool first = kg < klen0;
    const u16* pa = first ? (aw0 + kg) : (aw1 + (kg - klen0));
    av0 = *(const uint4*)pa;
    av1 = *(const uint4*)(pa + 8);
    if constexpr (WF32) {
      const float* pb = first ? (bw0_f + kg) : (bw1_f + (kg - klen0));
      xf0 = *(const float4*)pb;
      xf1 = *(const float4*)(pb + 4);
      xf2 = *(const float4*)(pb + 8);
      xf3 = *(const float4*)(pb + 12);
    } else {
      const u16* pb = first ? (bw0_h + kg) : (bw1_h + (kg - klen0));
      bv0 = *(const uint4*)pb;
      bv1 = *(const uint4*)(pb + 8);
    }
  };

  float4v acc00 = {}, acc01 = {}, acc10 = {}, acc11 = {};
  const int nch = d.Ktot >> 6;
  load_chunk(0);
  for (int kc = 0; kc < nch; ++kc) {
    if constexpr (WF32) {
      bv0 = make_uint4(pack2(xf0.x, xf0.y), pack2(xf0.z, xf0.w),
                       pack2(xf1.x, xf1.y), pack2(xf1.z, xf1.w));
      bv1 = make_uint4(pack2(xf2.x, xf2.y), pack2(xf2.z, xf2.w),
                       pack2(xf3.x, xf3.y), pack2(xf3.z, xf3.w));
    }
    __syncthreads();  // previous chunk's LDS readers done
    *(uint4*)&As[r][q * 16]     = av0;
    *(uint4*)&As[r][q * 16 + 8] = av1;
    *(uint4*)&Bs[r][q * 16]     = bv0;
    *(uint4*)&Bs[r][q * 16 + 8] = bv1;
    __syncthreads();
    if (kc + 1 < nch) load_chunk(kc + 1);  // in flight across MFMA below
#pragma unroll
    for (int ks = 0; ks < 2; ++ks) {
      const int kb = ks * 32 + quad * 8;
      short8 a0 = *(const short8*)&As[wm + l16][kb];
      short8 a1 = *(const short8*)&As[wm + 16 + l16][kb];
      short8 b0 = *(const short8*)&Bs[wn + l16][kb];
      short8 b1 = *(const short8*)&Bs[wn + 16 + l16][kb];
      acc00 = __builtin_amdgcn_mfma_f32_16x16x32_bf16(a0, b0, acc00, 0, 0, 0);
      acc01 = __builtin_amdgcn_mfma_f32_16x16x32_bf16(a0, b1, acc01, 0, 0, 0);
      acc10 = __builtin_amdgcn_mfma_f32_16x16x32_bf16(a1, b0, acc10, 0, 0, 0);
      acc11 = __builtin_amdgcn_mfma_f32_16x16x32_bf16(a1, b1, acc11, 0, 0, 0);
    }
  }

  // spill gates to LDS (C/D layout: col = lane&15, row = quad*4 + reg)
#pragma unroll
  for (int rr = 0; rr < 4; ++rr) {
    Gs[wm + quad * 4 + rr][wn + l16]           = acc00[rr];
    Gs[wm + quad * 4 + rr][wn + 16 + l16]      = acc01[rr];
    Gs[wm + 16 + quad * 4 + rr][wn + l16]      = acc10[rr];
    Gs[wm + 16 + quad * 4 + rr][wn + 16 + l16] = acc11[rr];
  }
  __syncthreads();

  // fused LSTM cell: 64 batches x 16 units; local col 4u+g = gate g of unit ub+u
#pragma unroll
  for (int it = 0; it < 4; ++it) {
    const int p = tid + it * 256;
    const int bl = p >> 4;
    const int u = p & 15;
    const int J = ub + u;
    const int bg = m0 + bl;
    const float4v g = *(const float4v*)&Gs[bl][u * 4];
    float pi = g[0] + d.bias[J];
    float pf = g[1] + d.bias[H_ + J];
    float pg = g[2] + d.bias[2 * H_ + J];
    float po = g[3] + d.bias[3 * H_ + J];
    if (d.inp != nullptr) {
      const float iv = d.inp[bg];
      pi += iv * d.wcol[J];
      pf += iv * d.wcol[H_ + J];
      pg += iv * d.wcol[2 * H_ + J];
      po += iv * d.wcol[3 * H_ + J];
    }
    const size_t idx = (size_t)bg * H_ + J;
    const float cc = d.c[idx];
    const float cn = sigm(pf) * cc + sigm(pi) * tanh_(pg);
    d.c[idx] = cn;
    d.h[idx] = f2bf(sigm(po) * tanh_(cn));
  }
}

// Whole network in ONE plain launch: 512 blocks x 256 threads.
// __launch_bounds__(256,2) + 35.8 KB LDS -> 2 blocks/CU, all 512 co-resident;
// manual gsync() replaces grid.sync (cooperative launch failed in harness).
// Encoder tick u: blocks 0..255 = L0(t=u), 256..511 = L1(t=u-1); gsync.
// Decoder: L0 -> gsync -> L1 -> gsync -> fc -> gsync.
template <bool WF32>
__global__ __launch_bounds__(256, 2) void seq2seq_kernel(Params P)
{
  __shared__ u16 As[64][72];   // +8 pad: free 2-way bank conflicts only (m136)
  __shared__ u16 Bs[64][72];
  __shared__ float Gs[64][68];

  const int bid = blockIdx.x;
  const int tid = threadIdx.x;
  const int gtid = bid * 256 + tid;
  const int gstr = gridDim.x * 256;

  // prologue: zero states, convert X (+ weights) to bf16
  for (int i = gtid; i < P.zero16; i += gstr)
    P.zbase[i] = make_uint4(0u, 0u, 0u, 0u);
  for (int i = gtid; i < B_ * S_ * D_; i += gstr) P.XB[i] = f2bf(P.X[i]);
  if constexpr (!WF32) {
    const float* src[7] = {P.eWih0, P.eWhh0, P.eWih1, P.eWhh1,
                           P.dWhh0, P.dWih1, P.dWhh1};
    u16* dst[7] = {P.Wc0, P.Wc1, P.Wc2, P.Wc3, P.Wc4, P.Wc5, P.Wc6};
    const int n[7] = {G4 * D_, G4 * H_, G4 * H_, G4 * H_,
                      G4 * H_, G4 * H_, G4 * H_};
    for (int w = 0; w < 7; ++w)
      for (int i = gtid; i < n[w]; i += gstr) dst[w][i] = f2bf(src[w][i]);
  }
  gsync(P.bar, bid);

  u16* h0buf[2] = {P.h0a, P.h0b};
  u16* h1buf[2] = {P.h1a, P.h1b};

  // encoder, layer-pipelined: tick u = L0(t=u) + L1(t=u-1).
  for (int u = 0; u <= S_; ++u) {
    if (bid < 256) {
      if (u < S_) {
        const int t = u;
        LayerDesc d;
        d.A0 = P.XB + t * D_; d.lda0 = S_ * D_;
        d.A1 = h0buf[t & 1]; d.lda1 = H_; d.klen0 = D_;
        d.W0 = WF32 ? (const void*)P.eWih0 : (const void*)P.Wc0; d.ldw0 = D_;
        d.W1 = WF32 ? (const void*)P.eWhh0 : (const void*)P.Wc1; d.ldw1 = H_;
        d.Ktot = 1088;
        d.bias = P.eb0; d.wcol = nullptr; d.inp = nullptr;
        d.c = P.C0; d.h = h0buf[(t + 1) & 1];
        layer_tile<WF32>(d, bid, tid, As, Bs, Gs);
      }
    } else {
      if (u >= 1) {
        const int t = u - 1;
        LayerDesc d;
        d.A0 = h0buf[(t + 1) & 1]; d.lda0 = H_;
        d.A1 = h1buf[t & 1]; d.lda1 = H_; d.klen0 = H_;
        d.W0 = WF32 ? (const void*)P.eWih1 : (const void*)P.Wc2; d.ldw0 = H_;
        d.W1 = WF32 ? (const void*)P.eWhh1 : (const void*)P.Wc3; d.ldw1 = H_;
        d.Ktot = 2048;
        d.bias = P.eb1; d.wcol = nullptr; d.inp = nullptr;
        d.c = P.C1; d.h = h1buf[(t + 1) & 1];
        layer_tile<WF32>(d, bid - 256, tid, As, Bs, Gs);
      }
    }
    gsync(P.bar, bid);
  }

  // decoder: sequential (pred feedback)
  for (int t = 0; t < TOUT; ++t) {
    u16* h0i = h0buf[t & 1]; u16* h0o = h0buf[(t + 1) & 1];
    u16* h1i = h1buf[t & 1]; u16* h1o = h1buf[(t + 1) & 1];
    if (bid < 256) {
      LayerDesc d;
      d.A0 = h0i; d.lda0 = H_; d.A1 = h0i; d.lda1 = H_; d.klen0 = H_;
      d.W0 = WF32 ? (const void*)P.dWhh0 : (const void*)P.Wc4; d.ldw0 = H_;
      d.W1 = d.W0; d.ldw1 = H_;
      d.Ktot = 1024;
      d.bias = P.db0; d.wcol = P.dWih0; d.inp = P.INP;
      d.c = P.C0; d.h = h0o;
      layer_tile<WF32>(d, bid, tid, As, Bs, Gs);
    }
    gsync(P.bar, bid);
    if (bid < 256) {
      LayerDesc d;
      d.A0 = h0o; d.lda0 = H_; d.A1 = h1i; d.lda1 = H_; d.klen0 = H_;
      d.W0 = WF32 ? (const void*)P.dWih1 : (const void*)P.Wc5; d.ldw0 = H_;
      d.W1 = WF32 ? (const void*)P.dWhh1 : (const void*)P.Wc6; d.ldw1 = H_;
      d.Ktot = 2048;
      d.bias = P.db1; d.wcol = nullptr; d.inp = nullptr;
      d.c = P.C1; d.h = h1o;
      layer_tile<WF32>(d, bid, tid, As, Bs, Gs);
    }
    gsync(P.bar, bid);
    if (bid < 256) {
      // fc: pred[bid] = fc_W . h1o[bid] + fc_b
      const u16* hr = h1o + (size_t)bid * H_ + tid * 4;
      float s = 0.f;
#pragma unroll
      for (int j = 0; j < 4; ++j) s += bf2f(hr[j]) * P.fcW[tid * 4 + j];
#pragma unroll
      for (int o = 32; o > 0; o >>= 1) s += __shfl_down(s, o, 64);
      float* red = (float*)&Gs[0][0];
      if ((tid & 63) == 0) red[tid >> 6] = s;
      __syncthreads();
      if (tid == 0) {
        const float p = red[0] + red[1] + red[2] + red[3] + P.fcb[0];
        P.out[(size_t)bid * TOUT + t] = p;
        P.INP[bid] = p;
      }
    }
    gsync(P.bar, bid);
  }
}

extern "C" void kernel_launch(void* const* d_in, const int* in_sizes, int n_in,
                              void* d_out, int out_size, void* d_ws, size_t ws_size,
                              hipStream_t stream)
{
  Params P;
  P.X     = (const float*)d_in[0];
  P.eWih0 = (const float*)d_in[1];
  P.eWhh0 = (const float*)d_in[2];
  P.eb0   = (const float*)d_in[3];
  P.eWih1 = (const float*)d_in[4];
  P.eWhh1 = (const float*)d_in[5];
  P.eb1   = (const float*)d_in[6];
  P.dWih0 = (const float*)d_in[7];
  P.dWhh0 = (const float*)d_in[8];
  P.db0   = (const float*)d_in[9];
  P.dWih1 = (const float*)d_in[10];
  P.dWhh1 = (const float*)d_in[11];
  P.db1   = (const float*)d_in[12];
  P.fcW   = (const float*)d_in[13];
  P.fcb   = (const float*)d_in[14];
  P.out   = (float*)d_out;

  char* ws = (char*)d_ws;
  size_t off = 0;
  auto alloc = [&](size_t bytes) -> void* {
    void* p = ws + off;
    off += (bytes + 255) & ~(size_t)255;
    return p;
  };
  // barrier storage first (pre-zeroed by async memset below, NOT by the kernel)
  P.bar = (unsigned*)alloc(4096);
  // state block (zeroed in-kernel every call)
  char* zstart = ws + off;
  P.h0a = (u16*)alloc((size_t)B_ * H_ * 2);
  P.h0b = (u16*)alloc((size_t)B_ * H_ * 2);
  P.h1a = (u16*)alloc((size_t)B_ * H_ * 2);
  P.h1b = (u16*)alloc((size_t)B_ * H_ * 2);
  P.C0  = (float*)alloc((size_t)B_ * H_ * 4);
  P.C1  = (float*)alloc((size_t)B_ * H_ * 4);
  P.INP = (float*)alloc(B_ * 4);
  P.zbase = (uint4*)zstart;
  P.zero16 = (int)(((ws + off) - zstart) / 16);
  P.XB = (u16*)alloc((size_t)B_ * S_ * D_ * 2);
  // bf16 weight copies (fast path), original flat layouts
  P.Wc0 = (u16*)alloc((size_t)G4 * D_ * 2);
  P.Wc1 = (u16*)alloc((size_t)G4 * H_ * 2);
  P.Wc2 = (u16*)alloc((size_t)G4 * H_ * 2);
  P.Wc3 = (u16*)alloc((size_t)G4 * H_ * 2);
  P.Wc4 = (u16*)alloc((size_t)G4 * H_ * 2);
  P.Wc5 = (u16*)alloc((size_t)G4 * H_ * 2);
  P.Wc6 = (u16*)alloc((size_t)G4 * H_ * 2);
  const bool fast = (ws_size >= off);

  hipMemsetAsync(P.bar, 0, 4096, stream);
  if (fast)
    seq2seq_kernel<false><<<dim3(512), dim3(256), 0, stream>>>(P);
  else
    seq2seq_kernel<true><<<dim3(512), dim3(256), 0, stream>>>(P);
}

// Round 9
// 8883.934 us; speedup vs baseline: 5.3859x; 5.3859x over previous
//
#include <hip/hip_runtime.h>

#define B_ 256
#define S_ 256
#define D_ 64
#define H_ 1024
#define G4 4096
#define TOUT 32

typedef unsigned short u16;
typedef unsigned int u32;
typedef unsigned long long u64t;
typedef __attribute__((ext_vector_type(8))) short short8;
typedef __attribute__((ext_vector_type(4))) float float4v;

__device__ __forceinline__ float bf2f(u16 b) {
  return __uint_as_float(((u32)b) << 16);
}
__device__ __forceinline__ u16 f2bf(float f) {
  u32 u = __float_as_uint(f);
  return (u16)((u + 0x7fffu + ((u >> 16) & 1u)) >> 16);
}
__device__ __forceinline__ u32 pack2(float a, float b) {
  return (u32)f2bf(a) | ((u32)f2bf(b) << 16);
}
__device__ __forceinline__ float sigm(float x) {
  return 1.f / (1.f + __expf(-x));
}
__device__ __forceinline__ float tanh_(float x) {
  float xc = fminf(fmaxf(x, -15.f), 15.f);
  float e = __expf(2.f * xc);
  return (e - 1.f) / (e + 1.f);
}

// Coherent (sc0 sc1) accesses: bypass L1/L2, ordered at the device coherent
// point. RELAXED -> compiler emits NO buffer_wbl2 / buffer_inv (the round-8
// killer). Used ONLY for cross-block-mutable data (h, c, INP).
__device__ __forceinline__ u32 cload4(const void* p) {
  return __hip_atomic_load((const u32*)p, __ATOMIC_RELAXED, __HIP_MEMORY_SCOPE_AGENT);
}
__device__ __forceinline__ u64t cload8(const void* p) {
  return __hip_atomic_load((const u64t*)p, __ATOMIC_RELAXED, __HIP_MEMORY_SCOPE_AGENT);
}
__device__ __forceinline__ void cstore4(void* p, u32 v) {
  __hip_atomic_store((u32*)p, v, __ATOMIC_RELAXED, __HIP_MEMORY_SCOPE_AGENT);
}
__device__ __forceinline__ void cstore8(void* p, u64t v) {
  __hip_atomic_store((u64t*)p, v, __ATOMIC_RELAXED, __HIP_MEMORY_SCOPE_AGENT);
}

// Two-level grid barrier (8 groups x 64 + top 8), sense-reversing, RELAXED
// atomics only. Release: __syncthreads() lowers to "s_waitcnt vmcnt(0)
// lgkmcnt(0); s_barrier" for every wave, so all coherent stores are at L3
// before the arrival add. No cache maintenance instructions anywhere.
__device__ __forceinline__ void gsync(u32* bar, int bid) {
  __builtin_amdgcn_s_waitcnt(0);
  __syncthreads();
  if (threadIdx.x == 0) {
    const int grp = bid & 7;
    u32* gcnt = bar + grp * 32;
    u32* ggen = bar + 256 + grp * 32;
    u32* tcnt = bar + 512;
    u32* tgen = bar + 544;
    const u32 g = cload4(ggen);
    const u32 prev =
        __hip_atomic_fetch_add(gcnt, 1u, __ATOMIC_RELAXED, __HIP_MEMORY_SCOPE_AGENT);
    if (prev == 63) {  // group leader
      const u32 tg = cload4(tgen);
      const u32 p2 =
          __hip_atomic_fetch_add(tcnt, 1u, __ATOMIC_RELAXED, __HIP_MEMORY_SCOPE_AGENT);
      if (p2 == 7) {
        cstore4(tcnt, 0u);
        __builtin_amdgcn_s_waitcnt(0);  // reset visible before release
        __hip_atomic_fetch_add(tgen, 1u, __ATOMIC_RELAXED, __HIP_MEMORY_SCOPE_AGENT);
      } else {
        while (cload4(tgen) == tg) __builtin_amdgcn_s_sleep(2);
      }
      cstore4(gcnt, 0u);
      __builtin_amdgcn_s_waitcnt(0);
      __hip_atomic_fetch_add(ggen, 1u, __ATOMIC_RELAXED, __HIP_MEMORY_SCOPE_AGENT);
    } else {
      while (cload4(ggen) == g) __builtin_amdgcn_s_sleep(2);
    }
  }
  __syncthreads();
}

struct LayerDesc {
  const u16* Ax; int ldax; int kx;    // cached A segment (X); kx=0 if none
  const u16* Ah1; int k1;             // coherent h segment 1 (row stride H_)
  const u16* Ah2;                     // coherent h segment 2 (row stride H_)
  const void* W0; int ldw0; int kb0;  // weights (ORIGINAL torch layout); k<kb0 -> W0
  const void* W1; int ldw1; int Ktot;
  const float* bias;                  // fp32 [4096] gate-blocked, cached
  const float* wcol;                  // fp32 [4096] dec input col, or null
  const float* inp;                   // coherent fp32 [B_], or null
  float* c;                           // coherent fp32 state
  u16* h;                             // coherent bf16 output
};

struct Params {
  const float *X, *eWih0, *eWhh0, *eb0, *eWih1, *eWhh1, *eb1;
  const float *dWih0, *dWhh0, *db0, *dWih1, *dWhh1, *db1, *fcW, *fcb;
  float* out;
  u32* bar;
  u64t* zbase; int nz8;
  u16 *h0a, *h0b, *h1a, *h1b;
  float *C0, *C1, *INP;
  u16* XB;
  u16* Wc[7];  // eWih0,eWhh0,eWih1,eWhh1,dWhh0,dWih1,dWhh1 (bf16 copies)
};

// 64x64 tile of one LSTM layer step (round-3 proven body + segmented A):
// gates = [A] @ [W]^T + bias (+inp*wcol), fused cell epilogue.
// A = [Ax cached | Ah1 coherent | Ah2 coherent]; W cached (L2-resident).
template <bool WF32>
__device__ void layer_tile(const LayerDesc& d, int tile, int tid,
                           u16 (*As)[72], u16 (*Bs)[72], float (*Gs)[68])
{
  const int m0 = (tile >> 6) * 64;
  const int n0 = (tile & 63) * 64;
  const int ub = n0 >> 2;
  const int r = tid >> 2;
  const int q = tid & 3;
  const int lane = tid & 63;
  const int wv = tid >> 6;
  const int wm = (wv >> 1) * 32;
  const int wn = (wv & 1) * 32;
  const int l16 = lane & 15;
  const int quad = lane >> 4;

  const u16* axp = d.Ax ? (d.Ax + (size_t)(m0 + r) * d.ldax) : nullptr;
  const u16* ah1 = d.Ah1 + (size_t)(m0 + r) * H_;
  const u16* ah2 = d.Ah2 ? (d.Ah2 + (size_t)(m0 + r) * H_) : nullptr;
  const int orow = (r & 3) * H_ + ub + (r >> 2);  // gate-col n0+r -> W row
  const u16* bw0_h = (const u16*)d.W0 + (size_t)orow * d.ldw0;
  const u16* bw1_h = (const u16*)d.W1 + (size_t)orow * d.ldw1;
  const float* bw0_f = (const float*)d.W0 + (size_t)orow * d.ldw0;
  const float* bw1_f = (const float*)d.W1 + (size_t)orow * d.ldw1;

  uint4 av0, av1, bv0, bv1;
  float4 xf0, xf1, xf2, xf3;

  auto load_chunk = [&](int kc) {
    const int kg = kc * 64 + q * 16;
    if (kg < d.kx) {                       // cached X segment
      const u16* pa = axp + kg;
      av0 = *(const uint4*)pa;
      av1 = *(const uint4*)(pa + 8);
    } else {                               // coherent h segments
      const int kh = kg - d.kx;
      const u16* hp = (kh < d.k1) ? (ah1 + kh) : (ah2 + (kh - d.k1));
      const u64t a = cload8(hp);
      const u64t b = cload8(hp + 4);
      const u64t c2 = cload8(hp + 8);
      const u64t e = cload8(hp + 12);
      av0 = make_uint4((u32)a, (u32)(a >> 32), (u32)b, (u32)(b >> 32));
      av1 = make_uint4((u32)c2, (u32)(c2 >> 32), (u32)e, (u32)(e >> 32));
    }
    if constexpr (WF32) {
      const float* pb = (kg < d.kb0) ? (bw0_f + kg) : (bw1_f + (kg - d.kb0));
      xf0 = *(const float4*)pb;
      xf1 = *(const float4*)(pb + 4);
      xf2 = *(const float4*)(pb + 8);
      xf3 = *(const float4*)(pb + 12);
    } else {
      const u16* pb = (kg < d.kb0) ? (bw0_h + kg) : (bw1_h + (kg - d.kb0));
      bv0 = *(const uint4*)pb;
      bv1 = *(const uint4*)(pb + 8);
    }
  };

  float4v acc00 = {}, acc01 = {}, acc10 = {}, acc11 = {};
  const int nch = d.Ktot >> 6;
  load_chunk(0);
  for (int kc = 0; kc < nch; ++kc) {
    if constexpr (WF32) {
      bv0 = make_uint4(pack2(xf0.x, xf0.y), pack2(xf0.z, xf0.w),
                       pack2(xf1.x, xf1.y), pack2(xf1.z, xf1.w));
      bv1 = make_uint4(pack2(xf2.x, xf2.y), pack2(xf2.z, xf2.w),
                       pack2(xf3.x, xf3.y), pack2(xf3.z, xf3.w));
    }
    __syncthreads();
    *(uint4*)&As[r][q * 16]     = av0;
    *(uint4*)&As[r][q * 16 + 8] = av1;
    *(uint4*)&Bs[r][q * 16]     = bv0;
    *(uint4*)&Bs[r][q * 16 + 8] = bv1;
    __syncthreads();
    if (kc + 1 < nch) load_chunk(kc + 1);
#pragma unroll
    for (int ks = 0; ks < 2; ++ks) {
      const int kb = ks * 32 + quad * 8;
      short8 a0 = *(const short8*)&As[wm + l16][kb];
      short8 a1 = *(const short8*)&As[wm + 16 + l16][kb];
      short8 b0 = *(const short8*)&Bs[wn + l16][kb];
      short8 b1 = *(const short8*)&Bs[wn + 16 + l16][kb];
      acc00 = __builtin_amdgcn_mfma_f32_16x16x32_bf16(a0, b0, acc00, 0, 0, 0);
      acc01 = __builtin_amdgcn_mfma_f32_16x16x32_bf16(a0, b1, acc01, 0, 0, 0);
      acc10 = __builtin_amdgcn_mfma_f32_16x16x32_bf16(a1, b0, acc10, 0, 0, 0);
      acc11 = __builtin_amdgcn_mfma_f32_16x16x32_bf16(a1, b1, acc11, 0, 0, 0);
    }
  }

  // spill gates (C/D layout: col = lane&15, row = quad*4 + reg)
#pragma unroll
  for (int rr = 0; rr < 4; ++rr) {
    Gs[wm + quad * 4 + rr][wn + l16]           = acc00[rr];
    Gs[wm + quad * 4 + rr][wn + 16 + l16]      = acc01[rr];
    Gs[wm + 16 + quad * 4 + rr][wn + l16]      = acc10[rr];
    Gs[wm + 16 + quad * 4 + rr][wn + 16 + l16] = acc11[rr];
  }
  __syncthreads();

  // fused LSTM cell: 64 batches x 16 units; thread handles a batch x unit-PAIR
  // so h (u32) and c (u64) go out as single coherent stores.
#pragma unroll
  for (int it = 0; it < 2; ++it) {
    const int p = tid + it * 256;
    const int bl = p >> 3;     // batch-local 0..63
    const int up = p & 7;      // unit pair 0..7
    const int J = ub + 2 * up;
    const int bg = m0 + bl;
    const float4v g0 = *(const float4v*)&Gs[bl][8 * up];
    const float4v g1 = *(const float4v*)&Gs[bl][8 * up + 4];
    float iv = 0.f;
    if (d.inp != nullptr) iv = __uint_as_float(cload4(&d.inp[bg]));
    const u64t cw = cload8(&d.c[(size_t)bg * H_ + J]);
    float cv[2] = {__uint_as_float((u32)cw), __uint_as_float((u32)(cw >> 32))};
    const float4v gg[2] = {g0, g1};
    float hv[2];
#pragma unroll
    for (int s = 0; s < 2; ++s) {
      const int Js = J + s;
      float pi = gg[s][0] + d.bias[Js];
      float pf = gg[s][1] + d.bias[H_ + Js];
      float pg = gg[s][2] + d.bias[2 * H_ + Js];
      float po = gg[s][3] + d.bias[3 * H_ + Js];
      if (d.inp != nullptr) {
        pi += iv * d.wcol[Js];
        pf += iv * d.wcol[H_ + Js];
        pg += iv * d.wcol[2 * H_ + Js];
        po += iv * d.wcol[3 * H_ + Js];
      }
      const float cn = sigm(pf) * cv[s] + sigm(pi) * tanh_(pg);
      cv[s] = cn;
      hv[s] = sigm(po) * tanh_(cn);
    }
    cstore8(&d.c[(size_t)bg * H_ + J],
            (u64t)__float_as_uint(cv[0]) | ((u64t)__float_as_uint(cv[1]) << 32));
    cstore4(&d.h[(size_t)bg * H_ + J], pack2(hv[0], hv[1]));
  }
}

// ONE plain launch: 512 blocks x 256 thr, 2 blocks/CU (all co-resident; proven
// round 8). Encoder tick u: blocks 0..255 = L0(t=u), 256..511 = L1(t=u-1).
// Decoder: L0 (lower) -> sync -> L1 (UPPER blocks: same c1 owners as encoder)
// -> sync -> fc (lower) -> sync.
template <bool WF32>
__global__ __launch_bounds__(256, 2) void seq2seq_kernel(Params P)
{
  __shared__ u16 As[64][72];
  __shared__ u16 Bs[64][72];
  __shared__ float Gs[64][68];
  __shared__ float red[4];

  const int bid = blockIdx.x;
  const int tid = threadIdx.x;
  const int gtid = bid * 256 + tid;
  const int gstr = gridDim.x * 256;

  // prologue: everything cross-visible written with coherent stores
  for (int i = gtid; i < P.nz8; i += gstr) cstore8(P.zbase + i, 0ull);
  for (int i = gtid; i < B_ * S_ * D_ / 4; i += gstr) {
    const float4 v = *((const float4*)P.X + i);
    cstore8((u64t*)P.XB + i,
            (u64t)pack2(v.x, v.y) | ((u64t)pack2(v.z, v.w) << 32));
  }
  if constexpr (!WF32) {
    const float* src[7] = {P.eWih0, P.eWhh0, P.eWih1, P.eWhh1,
                           P.dWhh0, P.dWih1, P.dWhh1};
    const int n4[7] = {G4 * D_ / 4, G4 * H_ / 4, G4 * H_ / 4, G4 * H_ / 4,
                       G4 * H_ / 4, G4 * H_ / 4, G4 * H_ / 4};
    for (int w = 0; w < 7; ++w) {
      u64t* dst = (u64t*)P.Wc[w];
      for (int i = gtid; i < n4[w]; i += gstr) {
        const float4 v = *((const float4*)src[w] + i);
        cstore8(dst + i,
                (u64t)pack2(v.x, v.y) | ((u64t)pack2(v.z, v.w) << 32));
      }
    }
  }
  gsync(P.bar, bid);

  u16* h0buf[2] = {P.h0a, P.h0b};
  u16* h1buf[2] = {P.h1a, P.h1b};

  // encoder, layer-pipelined
  for (int u = 0; u <= S_; ++u) {
    if (bid < 256) {
      if (u < S_) {
        const int t = u;
        LayerDesc d;
        d.Ax = P.XB + t * D_; d.ldax = S_ * D_; d.kx = D_;
        d.Ah1 = h0buf[t & 1]; d.k1 = H_; d.Ah2 = nullptr;
        d.W0 = WF32 ? (const void*)P.eWih0 : (const void*)P.Wc[0]; d.ldw0 = D_;
        d.kb0 = D_;
        d.W1 = WF32 ? (const void*)P.eWhh0 : (const void*)P.Wc[1]; d.ldw1 = H_;
        d.Ktot = 1088;
        d.bias = P.eb0; d.wcol = nullptr; d.inp = nullptr;
        d.c = P.C0; d.h = h0buf[(t + 1) & 1];
        layer_tile<WF32>(d, bid, tid, As, Bs, Gs);
      }
    } else {
      if (u >= 1) {
        const int t = u - 1;
        LayerDesc d;
        d.Ax = nullptr; d.ldax = 0; d.kx = 0;
        d.Ah1 = h0buf[(t + 1) & 1]; d.k1 = H_; d.Ah2 = h1buf[t & 1];
        d.W0 = WF32 ? (const void*)P.eWih1 : (const void*)P.Wc[2]; d.ldw0 = H_;
        d.kb0 = H_;
        d.W1 = WF32 ? (const void*)P.eWhh1 : (const void*)P.Wc[3]; d.ldw1 = H_;
        d.Ktot = 2048;
        d.bias = P.eb1; d.wcol = nullptr; d.inp = nullptr;
        d.c = P.C1; d.h = h1buf[(t + 1) & 1];
        layer_tile<WF32>(d, bid - 256, tid, As, Bs, Gs);
      }
    }
    gsync(P.bar, bid);
  }

  // decoder: sequential
  for (int t = 0; t < TOUT; ++t) {
    u16* h0i = h0buf[t & 1]; u16* h0o = h0buf[(t + 1) & 1];
    u16* h1i = h1buf[t & 1]; u16* h1o = h1buf[(t + 1) & 1];
    if (bid < 256) {
      LayerDesc d;
      d.Ax = nullptr; d.ldax = 0; d.kx = 0;
      d.Ah1 = h0i; d.k1 = H_; d.Ah2 = nullptr;
      d.W0 = WF32 ? (const void*)P.dWhh0 : (const void*)P.Wc[4]; d.ldw0 = H_;
      d.kb0 = H_;
      d.W1 = d.W0; d.ldw1 = H_;
      d.Ktot = 1024;
      d.bias = P.db0; d.wcol = P.dWih0; d.inp = P.INP;
      d.c = P.C0; d.h = h0o;
      layer_tile<WF32>(d, bid, tid, As, Bs, Gs);
    }
    gsync(P.bar, bid);
    if (bid >= 256) {  // SAME blocks as encoder L1 -> c1 stays block-private
      LayerDesc d;
      d.Ax = nullptr; d.ldax = 0; d.kx = 0;
      d.Ah1 = h0o; d.k1 = H_; d.Ah2 = h1i;
      d.W0 = WF32 ? (const void*)P.dWih1 : (const void*)P.Wc[5]; d.ldw0 = H_;
      d.kb0 = H_;
      d.W1 = WF32 ? (const void*)P.dWhh1 : (const void*)P.Wc[6]; d.ldw1 = H_;
      d.Ktot = 2048;
      d.bias = P.db1; d.wcol = nullptr; d.inp = nullptr;
      d.c = P.C1; d.h = h1o;
      layer_tile<WF32>(d, bid - 256, tid, As, Bs, Gs);
    }
    gsync(P.bar, bid);
    if (bid < 256) {
      // fc: pred[bid] = fc_W . h1o[bid] + fc_b  (coherent h read)
      const u16* hr = h1o + (size_t)bid * H_ + tid * 4;
      const u64t hv = cload8(hr);
      float s = bf2f((u16)hv) * P.fcW[tid * 4] +
                bf2f((u16)(hv >> 16)) * P.fcW[tid * 4 + 1] +
                bf2f((u16)(hv >> 32)) * P.fcW[tid * 4 + 2] +
                bf2f((u16)(hv >> 48)) * P.fcW[tid * 4 + 3];
#pragma unroll
      for (int o = 32; o > 0; o >>= 1) s += __shfl_down(s, o, 64);
      if ((tid & 63) == 0) red[tid >> 6] = s;
      __syncthreads();
      if (tid == 0) {
        const float pr = red[0] + red[1] + red[2] + red[3] + P.fcb[0];
        P.out[(size_t)bid * TOUT + t] = pr;
        cstore4(&P.INP[bid], __float_as_uint(pr));
      }
    }
    gsync(P.bar, bid);
  }
}

extern "C" void kernel_launch(void* const* d_in, const int* in_sizes, int n_in,
                              void* d_out, int out_size, void* d_ws, size_t ws_size,
                              hipStream_t stream)
{
  Params P;
  P.X     = (const float*)d_in[0];
  P.eWih0 = (const float*)d_in[1];
  P.eWhh0 = (const float*)d_in[2];
  P.eb0   = (const float*)d_in[3];
  P.eWih1 = (const float*)d_in[4];
  P.eWhh1 = (const float*)d_in[5];
  P.eb1   = (const float*)d_in[6];
  P.dWih0 = (const float*)d_in[7];
  P.dWhh0 = (const float*)d_in[8];
  P.db0   = (const float*)d_in[9];
  P.dWih1 = (const float*)d_in[10];
  P.dWhh1 = (const float*)d_in[11];
  P.db1   = (const float*)d_in[12];
  P.fcW   = (const float*)d_in[13];
  P.fcb   = (const float*)d_in[14];
  P.out   = (float*)d_out;

  char* ws = (char*)d_ws;
  size_t off = 0;
  auto alloc = [&](size_t bytes) -> void* {
    void* p = ws + off;
    off += (bytes + 255) & ~(size_t)255;
    return p;
  };
  P.bar = (u32*)alloc(4096);  // zeroed by async memset below
  char* zstart = ws + off;    // state block, zeroed in-kernel (coherent stores)
  P.h0a = (u16*)alloc((size_t)B_ * H_ * 2);
  P.h0b = (u16*)alloc((size_t)B_ * H_ * 2);
  P.h1a = (u16*)alloc((size_t)B_ * H_ * 2);
  P.h1b = (u16*)alloc((size_t)B_ * H_ * 2);
  P.C0  = (float*)alloc((size_t)B_ * H_ * 4);
  P.C1  = (float*)alloc((size_t)B_ * H_ * 4);
  P.INP = (float*)alloc(B_ * 4);
  P.zbase = (u64t*)zstart;
  P.nz8 = (int)(((ws + off) - zstart) / 8);
  P.XB = (u16*)alloc((size_t)B_ * S_ * D_ * 2);
  P.Wc[0] = (u16*)alloc((size_t)G4 * D_ * 2);
  for (int w = 1; w < 7; ++w) P.Wc[w] = (u16*)alloc((size_t)G4 * H_ * 2);
  const bool fast = (ws_size >= off);

  hipMemsetAsync(P.bar, 0, 4096, stream);
  if (fast)
    seq2seq_kernel<false><<<dim3(512), dim3(256), 0, stream>>>(P);
  else
    seq2seq_kernel<true><<<dim3(512), dim3(256), 0, stream>>>(P);
}